// Round 1
// 125.903 us; speedup vs baseline: 1.0467x; 1.0467x over previous
//
#include <hip/hip_runtime.h>
#include <hip/hip_bf16.h>
#include <math.h>

// Problem constants (B=4096 rows, D=768 features)
#define B_ROWS 4096
#define D_DIM  768

// 256x256 tile, BK=32, 8 waves, quad-buffered LDS, counted-vmcnt pipeline.
#define BM 256
#define BN 256
#define BK 32
#define NKT (D_DIM / BK)   // 24 K-tiles
#define NBUF 4

typedef __attribute__((ext_vector_type(8))) short bf16x8;  // 8 bf16 = 4 VGPRs (MFMA A/B frag)
typedef __attribute__((ext_vector_type(4))) float f32x4;   // MFMA C/D frag

__device__ __forceinline__ unsigned short f32_to_bf16(float x) {
    // round-to-nearest-even; inputs are finite normals
    unsigned int u = __float_as_uint(x);
    return (unsigned short)((u + 0x7fffu + ((u >> 16) & 1u)) >> 16);
}

// async global->LDS, 16 B per lane. LDS dest is WAVE-UNIFORM base; HW writes
// lane L's 16 B at base + L*16 (m97/m104-verified semantics).
__device__ __forceinline__ void async_copy16(const unsigned short* g, unsigned short* l) {
    __builtin_amdgcn_global_load_lds(
        (const __attribute__((address_space(1))) unsigned int*)g,
        (__attribute__((address_space(3))) unsigned int*)l,
        16, 0, 0);
}

// K1: per-row stats + fp32->bf16 conversion. One WAVE per row (4 rows/block).
__global__ void __launch_bounds__(256) rowstats_kernel(
    const float* __restrict__ P, const float* __restrict__ T,
    unsigned short* __restrict__ Pb, unsigned short* __restrict__ Tb,
    float* __restrict__ p_sq, float* __restrict__ t_sq,
    float* __restrict__ diagl, float* __restrict__ magr,
    float* __restrict__ rowsum)
{
    const int wave = threadIdx.x >> 6, lane = threadIdx.x & 63;
    const int i = blockIdx.x * 4 + wave;
    const f32x4* prow = (const f32x4*)(P + (size_t)i * D_DIM);
    const f32x4* trow = (const f32x4*)(T + (size_t)i * D_DIM);
    ushort4* pbrow = (ushort4*)(Pb + (size_t)i * D_DIM);
    ushort4* tbrow = (ushort4*)(Tb + (size_t)i * D_DIM);

    float psq = 0.f, tsq = 0.f, cr = 0.f, l1 = 0.f, tm = 0.f;
    #pragma unroll
    for (int u = 0; u < 3; ++u) {         // 192 float4 per row / 64 lanes
        const int c4 = u * 64 + lane;
        f32x4 p = prow[c4], t = trow[c4];
        #pragma unroll
        for (int k = 0; k < 4; ++k) {
            psq += p[k] * p[k]; tsq += t[k] * t[k]; cr += p[k] * t[k];
            l1 += fabsf(p[k] - t[k]); tm += fabsf(t[k]);
        }
        pbrow[c4] = make_ushort4(f32_to_bf16(p[0]), f32_to_bf16(p[1]),
                                 f32_to_bf16(p[2]), f32_to_bf16(p[3]));
        tbrow[c4] = make_ushort4(f32_to_bf16(t[0]), f32_to_bf16(t[1]),
                                 f32_to_bf16(t[2]), f32_to_bf16(t[3]));
    }
    #pragma unroll
    for (int m = 1; m < 64; m <<= 1) {
        psq += __shfl_xor(psq, m, 64);
        tsq += __shfl_xor(tsq, m, 64);
        cr  += __shfl_xor(cr,  m, 64);
        l1  += __shfl_xor(l1,  m, 64);
        tm  += __shfl_xor(tm,  m, 64);
    }
    if (lane == 0) {
        p_sq[i] = psq;
        t_sq[i] = tsq;
        float sq = fmaxf(psq + tsq - 2.0f * cr, 0.0f);
        diagl[i] = -sqrtf(sq) * 10.0f;    // logit_ii = -dist/0.1 (the LSE shift)
        magr[i]  = l1 / tm;
        rowsum[i] = 0.0f;
    }
}

// K2: bf16-MFMA cross GEMM, 256x256 tile, 8 waves (2Mx4N), BK=32,
// QUAD-buffered LDS (4 x 32 KB = 128 KB) with prefetch depth 3 and COUNTED
// s_waitcnt vmcnt(8) (never 0 in the main loop) -- the T3/T4 counted-vmcnt
// schedule from the 8-phase template, simplified to 1 tile/barrier.
//
// Race-freedom argument:
//  - stage(t+3) writes buf (t+3)&3 == (t-1)&3, whose readers (iteration t-1)
//    all passed the end-of-(t-1) barrier, and every barrier is preceded by
//    s_waitcnt lgkmcnt(0) + sched_barrier(0), so no wave carries in-flight
//    ds_reads across a barrier (rule #18 fence).
//  - vmcnt(8) at end of iter t allows only the 8 loads of tiles t+2,t+3 to
//    remain outstanding -> tile t+1 has fully landed before any wave enters
//    iteration t+1 (per-wave count: each wave issues exactly 4 loads/tile).
//  - prior stage into the same buffer (tile t-1) landed at end of iter t-2.
//
// LDS swizzle (both-sides-or-neither, rule #21): row stride is 64 B =
// 4 x 16 B chunks; reader lane (row16,quad) wants chunk=quad of row R.
// Linear layout would put quad q of rows R, R+2, ... on the same banks
// (16R mod 32 has period 2). Store chunk c at slot c ^ ((R>>1)&3) by
// pre-swizzling the per-lane GLOBAL source address (LDS dest stays linear
// for global_load_lds), read at slot quad ^ ((R>>1)&3): bank base becomes
// 16(R&1) + 4(q ^ ((R>>1)&3)) mod 32 -> period 8 -> 2-way max (free, m136).
__global__ void __launch_bounds__(512, 2) lse_gemm_kernel(
    const unsigned short* __restrict__ Pb, const unsigned short* __restrict__ Tb,
    const float* __restrict__ p_sq, const float* __restrict__ t_sq,
    const float* __restrict__ diagl, float* __restrict__ rowsum)
{
    // S[buf][0]=A tile (256x32 bf16), S[buf][1]=B tile. 4*2*16KB = 128 KB.
    __shared__ __align__(16) unsigned short S[NBUF][2][BM * BK];

    const int tid  = threadIdx.x;
    const int lane = tid & 63, wave = tid >> 6;

    // XCD-aware swizzle: 256 wgs, HW round-robins flat%8 over 8 XCDs.
    // Give XCD x a 4x8 tile panel: P-panel 1.5 MB + T-panel 3 MB ~ L2-resident.
    const int flat = blockIdx.x;
    const int xcd  = flat & 7;
    const int s    = flat >> 3;                  // 0..31: slot within XCD
    const int ti   = ((xcd >> 1) << 2) + (s >> 3);   // 0..15
    const int tj   = ((xcd & 1) << 3) + (s & 7);     // 0..15
    const int i0   = ti * BM, j0 = tj * BN;

    // compute mapping: 2x4 wave grid, per-wave output 128x64
    const int wm = wave >> 2, wn = wave & 3;
    const int row16 = lane & 15, quad = lane >> 4;

    // fragment LDS offsets (ushort units), chunk-XOR swizzled
    int aoff[8], boff[4];
    #pragma unroll
    for (int mt = 0; mt < 8; ++mt) {
        const int R = wm * 128 + mt * 16 + row16;
        aoff[mt] = R * BK + ((quad ^ ((R >> 1) & 3)) << 3);
    }
    #pragma unroll
    for (int nt = 0; nt < 4; ++nt) {
        const int R = wn * 64 + nt * 16 + row16;
        boff[nt] = R * BK + ((quad ^ ((R >> 1) & 3)) << 3);
    }

    // staging mapping: waves 0-3 stage A (64 rows each), waves 4-7 stage B.
    // Each wave: 4 loads/tile, one load = 16 rows x 64 B (lane L -> row L>>2,
    // chunk slot L&3). Global chunk is pre-swizzled: g = (L&3) ^ ((R>>1)&3).
    const bool isB = wave >= 4;
    const int  sw  = wave & 3;
    const int  q   = lane & 3;
    const unsigned short* gsrc = isB ? Tb : Pb;
    const int  r0g = isB ? j0 : i0;
    const unsigned short* gp[4];
    int lbase[4];
    #pragma unroll
    for (int j = 0; j < 4; ++j) {
        const int R = sw * 64 + j * 16 + (lane >> 2);   // local row 0..255
        const int g = q ^ ((R >> 1) & 3);
        gp[j] = gsrc + (size_t)(r0g + R) * D_DIM + g * 8;
        lbase[j] = (sw * 64 + j * 16) * BK;             // wave-uniform dest
    }

    f32x4 acc[8][4];
    #pragma unroll
    for (int a = 0; a < 8; ++a)
        #pragma unroll
        for (int b = 0; b < 4; ++b)
            acc[a][b] = (f32x4){0.f, 0.f, 0.f, 0.f};

    // one K-tile of MFMA work from buffer `buf` (12 ds_read_b128 + 32 MFMA)
    auto compute = [&](int buf) {
        const unsigned short* Ab = &S[buf][0][0];
        const unsigned short* Bb = &S[buf][1][0];
        bf16x8 a[8], b[4];
        #pragma unroll
        for (int mt = 0; mt < 8; ++mt) a[mt] = *(const bf16x8*)(Ab + aoff[mt]);
        #pragma unroll
        for (int nt = 0; nt < 4; ++nt) b[nt] = *(const bf16x8*)(Bb + boff[nt]);
        __builtin_amdgcn_s_setprio(1);
        #pragma unroll
        for (int mt = 0; mt < 8; ++mt)
            #pragma unroll
            for (int nt = 0; nt < 4; ++nt)
                acc[mt][nt] = __builtin_amdgcn_mfma_f32_16x16x32_bf16(
                    a[mt], b[nt], acc[mt][nt], 0, 0, 0);
        __builtin_amdgcn_s_setprio(0);
    };

    // prologue: stage tiles 0..2 (12 loads/wave); wait tile 0 (8 = tiles 1,2 in flight)
    #pragma unroll
    for (int t = 0; t < 3; ++t)
        #pragma unroll
        for (int j = 0; j < 4; ++j)
            async_copy16(gp[j] + t * BK, &S[t][isB][lbase[j]]);
    asm volatile("s_waitcnt vmcnt(8)" ::: "memory");
    __builtin_amdgcn_s_barrier();

    // main loop: t = 0..20. stage(t+3) -> compute(t) -> vmcnt(8): tile t+1 landed.
    for (int t = 0; t < NKT - 3; ++t) {
        const int pb = (t + 3) & 3;
        #pragma unroll
        for (int j = 0; j < 4; ++j)
            async_copy16(gp[j] + (t + 3) * BK, &S[pb][isB][lbase[j]]);
        compute(t & 3);
        __builtin_amdgcn_sched_barrier(0);
        asm volatile("s_waitcnt vmcnt(8) lgkmcnt(0)" ::: "memory");
        __builtin_amdgcn_s_barrier();
    }
    // drain: tiles 21,22,23 (vmcnt 4 -> 0 -> done)
    compute(21 & 3);
    __builtin_amdgcn_sched_barrier(0);
    asm volatile("s_waitcnt vmcnt(4) lgkmcnt(0)" ::: "memory");
    __builtin_amdgcn_s_barrier();
    compute(22 & 3);
    __builtin_amdgcn_sched_barrier(0);
    asm volatile("s_waitcnt vmcnt(0) lgkmcnt(0)" ::: "memory");
    __builtin_amdgcn_s_barrier();
    compute(23 & 3);

    // Epilogue: C/D layout col=lane&15, row=quad*4+reg (m89/m91-verified).
    // term = exp(logit_ij - logit_ii) via exp2f; max shifted log2-exp ~99 < 127.
    const float NT_LOG2E = -14.4269504089f;   // -(1/TEMP) * log2(e)
    const float LOG2E    = 1.44269504089f;
    float tsq_l[4];
    #pragma unroll
    for (int nt = 0; nt < 4; ++nt)
        tsq_l[nt] = t_sq[j0 + wn * 64 + nt * 16 + row16];

    #pragma unroll
    for (int mt = 0; mt < 8; ++mt) {
        #pragma unroll
        for (int r = 0; r < 4; ++r) {
            const int i = i0 + wm * 128 + mt * 16 + quad * 4 + r;
            const float psq = p_sq[i];
            const float c0  = -diagl[i] * LOG2E;  // -logit_ii in log2 domain
            float sfin = 0.f;
            #pragma unroll
            for (int nt = 0; nt < 4; ++nt) {
                float c  = acc[mt][nt][r];
                float sq = fmaxf(fmaf(-2.0f, c, psq + tsq_l[nt]), 0.0f);
                float d  = sqrtf(sq);
                float y  = fmaf(d, NT_LOG2E, c0);  // (logit-logit_ii)*log2e
                sfin += exp2f(y);
            }
            #pragma unroll
            for (int m = 1; m < 16; m <<= 1) sfin += __shfl_xor(sfin, m, 64);
            if (row16 == 0) atomicAdd(&rowsum[i], sfin);
        }
    }
}

// K3: final reduction to the 3 output scalars.
__global__ void __launch_bounds__(256) finalize_kernel(
    const float* __restrict__ rowsum, const float* __restrict__ magr,
    float* __restrict__ out)
{
    const int tid = threadIdx.x;
    double sc = 0.0, sm = 0.0;
    for (int i = tid; i < B_ROWS; i += 256) {
        sc += log((double)rowsum[i]);   // loss_i = log sum_j exp(logit_ij - logit_ii)
        sm += (double)magr[i];
    }
    #pragma unroll
    for (int m = 1; m < 64; m <<= 1) {
        sc += __shfl_xor(sc, m, 64);
        sm += __shfl_xor(sm, m, 64);
    }
    __shared__ double red[4][2];
    const int wave = tid >> 6, lane = tid & 63;
    if (lane == 0) { red[wave][0] = sc; red[wave][1] = sm; }
    __syncthreads();
    if (tid == 0) {
        sc = red[0][0] + red[1][0] + red[2][0] + red[3][0];
        sm = red[0][1] + red[1][1] + red[2][1] + red[3][1];
        double lc = sc / (double)B_ROWS;
        double lm = sm / (double)B_ROWS;
        out[0] = (float)(0.5 * lc + 0.5 * lm);  // LOSS_SCALE=1, LAMBD=0.5
        out[1] = (float)lc;
        out[2] = (float)lm;
    }
}

extern "C" void kernel_launch(void* const* d_in, const int* in_sizes, int n_in,
                              void* d_out, int out_size, void* d_ws, size_t ws_size,
                              hipStream_t stream) {
    const float* P = (const float*)d_in[0];   // predicted [4096,768] fp32
    const float* T = (const float*)d_in[1];   // target    [4096,768] fp32
    float* out = (float*)d_out;               // 3 fp32 scalars

    char* ws = (char*)d_ws;
    float* rowsum = (float*)ws;               ws += B_ROWS * sizeof(float);
    float* p_sq   = (float*)ws;               ws += B_ROWS * sizeof(float);
    float* t_sq   = (float*)ws;               ws += B_ROWS * sizeof(float);
    float* diagl  = (float*)ws;               ws += B_ROWS * sizeof(float);
    float* magr   = (float*)ws;               ws += B_ROWS * sizeof(float);
    unsigned short* Pb = (unsigned short*)ws; ws += (size_t)B_ROWS * D_DIM * 2;
    unsigned short* Tb = (unsigned short*)ws;

    rowstats_kernel<<<B_ROWS / 4, 256, 0, stream>>>(
        P, T, Pb, Tb, p_sq, t_sq, diagl, magr, rowsum);
    lse_gemm_kernel<<<(B_ROWS / BM) * (B_ROWS / BN), 512, 0, stream>>>(
        Pb, Tb, p_sq, t_sq, diagl, rowsum);
    finalize_kernel<<<1, 256, 0, stream>>>(rowsum, magr, out);
}